// Round 1
// baseline (25.754 us; speedup 1.0000x reference)
//
#include <hip/hip_runtime.h>

#define GDIM 7
#define CELLS 49          // 7*7
#define CH 30
#define BLK 256

__device__ __forceinline__ float iou_fn(float ax1, float ay1, float ax2, float ay2,
                                        float bx1, float by1, float bx2, float by2) {
    float ix1 = fmaxf(ax1, bx1);
    float iy1 = fmaxf(ay1, by1);
    float ix2 = fminf(ax2, bx2);
    float iy2 = fminf(ay2, by2);
    float iw = fmaxf(ix2 - ix1, 0.0f);
    float ih = fmaxf(iy2 - iy1, 0.0f);
    float inter = iw * ih;
    float aa = (ax2 - ax1) * (ay2 - ay1);
    float ab = (bx2 - bx1) * (by2 - by1);
    return inter > 0.0f ? inter / (aa + ab - inter) : 0.0f;
}

__global__ __launch_bounds__(BLK) void yolo_stage1(const float* __restrict__ pred,
                                                   const float* __restrict__ lab,
                                                   float* __restrict__ partial,
                                                   int total_cells) {
    int i = blockIdx.x * BLK + threadIdx.x;
    float per_cell = 0.0f;
    if (i < total_cells) {
        int b = i / CELLS;
        int cell = i - b * CELLS;
        int mr = cell / GDIM;          // first spatial dim (used for cx in ref)
        int nc = cell - mr * GDIM;     // second spatial dim (used for cy in ref)
        const float* p = pred + (size_t)b * (CH * CELLS) + cell;
        const float* l = lab  + (size_t)b * (CH * CELLS) + cell;

        float pv[10], lv[10];
        #pragma unroll
        for (int c = 0; c < 10; ++c) pv[c] = p[c * CELLS];
        #pragma unroll
        for (int c = 0; c < 10; ++c) lv[c] = l[c * CELLS];

        float cls = 0.0f;
        #pragma unroll
        for (int c = 10; c < CH; ++c) {
            float d = p[c * CELLS] - l[c * CELLS];
            cls = fmaf(d, d, cls);
        }

        float fm = (float)mr, fn = (float)nc;

        // ground-truth box (labels, off 0)
        float gcx = (lv[0] + fm) / 7.0f;
        float gcy = (lv[1] + fn) / 7.0f;
        float gx1 = gcx - lv[2] * 0.5f, gy1 = gcy - lv[3] * 0.5f;
        float gx2 = gcx + lv[2] * 0.5f, gy2 = gcy + lv[3] * 0.5f;

        // pred box 1 (off 0)
        float c1x = (pv[0] + fm) / 7.0f;
        float c1y = (pv[1] + fn) / 7.0f;
        float b1x1 = c1x - pv[2] * 0.5f, b1y1 = c1y - pv[3] * 0.5f;
        float b1x2 = c1x + pv[2] * 0.5f, b1y2 = c1y + pv[3] * 0.5f;

        // pred box 2 (off 5)
        float c2x = (pv[5] + fm) / 7.0f;
        float c2y = (pv[6] + fn) / 7.0f;
        float b2x1 = c2x - pv[7] * 0.5f, b2y1 = c2y - pv[8] * 0.5f;
        float b2x2 = c2x + pv[7] * 0.5f, b2y2 = c2y + pv[8] * 0.5f;

        float iou1 = iou_fn(b1x1, b1y1, b1x2, b1y2, gx1, gy1, gx2, gy2);
        float iou2 = iou_fn(b2x1, b2y1, b2x2, b2y2, gx1, gy1, gx2, gy2);
        bool use1 = iou1 >= iou2;

        float d0 = pv[0] - lv[0], d1 = pv[1] - lv[1];
        float s2 = sqrtf(pv[2]) - sqrtf(lv[2]);
        float s3 = sqrtf(pv[3]) - sqrtf(lv[3]);
        float coor1 = d0 * d0 + d1 * d1 + s2 * s2 + s3 * s3;

        float d5 = pv[5] - lv[5], d6 = pv[6] - lv[6];
        float s7 = sqrtf(pv[7]) - sqrtf(lv[7]);
        float s8 = sqrtf(pv[8]) - sqrtf(lv[8]);
        float coor2 = d5 * d5 + d6 * d6 + s7 * s7 + s8 * s8;

        float coor = 5.0f * (use1 ? coor1 : coor2);

        float e1 = pv[4] - iou1; e1 *= e1;
        float e2 = pv[9] - iou2; e2 *= e2;
        float obj_conf   = use1 ? e1 : e2;
        float noobj_obj  = 0.5f * (use1 ? e2 : e1);
        float noobj_none = 0.5f * (pv[4] * pv[4] + pv[9] * pv[9]);

        bool obj = (lv[4] == 1.0f);
        per_cell = obj ? (coor + obj_conf + noobj_obj + cls) : noobj_none;
    }

    // wave64 reduction
    float v = per_cell;
    #pragma unroll
    for (int off = 32; off > 0; off >>= 1) v += __shfl_down(v, off, 64);

    __shared__ float sdata[BLK / 64];
    int lane = threadIdx.x & 63;
    int wid  = threadIdx.x >> 6;
    if (lane == 0) sdata[wid] = v;
    __syncthreads();
    if (threadIdx.x == 0) {
        float s = 0.0f;
        #pragma unroll
        for (int w = 0; w < BLK / 64; ++w) s += sdata[w];
        partial[blockIdx.x] = s;
    }
}

__global__ __launch_bounds__(BLK) void yolo_stage2(const float* __restrict__ partial,
                                                   int n, float inv_b,
                                                   float* __restrict__ out) {
    float v = 0.0f;
    for (int i = threadIdx.x; i < n; i += BLK) v += partial[i];
    #pragma unroll
    for (int off = 32; off > 0; off >>= 1) v += __shfl_down(v, off, 64);

    __shared__ float sdata[BLK / 64];
    int lane = threadIdx.x & 63;
    int wid  = threadIdx.x >> 6;
    if (lane == 0) sdata[wid] = v;
    __syncthreads();
    if (threadIdx.x == 0) {
        float s = 0.0f;
        #pragma unroll
        for (int w = 0; w < BLK / 64; ++w) s += sdata[w];
        out[0] = s * inv_b;
    }
}

extern "C" void kernel_launch(void* const* d_in, const int* in_sizes, int n_in,
                              void* d_out, int out_size, void* d_ws, size_t ws_size,
                              hipStream_t stream) {
    const float* pred = (const float*)d_in[0];
    const float* lab  = (const float*)d_in[1];
    int B = in_sizes[0] / (CH * CELLS);          // 8192
    int total_cells = B * CELLS;                 // 401408
    int nblocks = (total_cells + BLK - 1) / BLK; // 1568

    float* partial = (float*)d_ws;
    float* out = (float*)d_out;

    yolo_stage1<<<nblocks, BLK, 0, stream>>>(pred, lab, partial, total_cells);
    yolo_stage2<<<1, BLK, 0, stream>>>(partial, nblocks, 1.0f / (float)B, out);
}